// Round 1
// baseline (679.735 us; speedup 1.0000x reference)
//
#include <hip/hip_runtime.h>

static constexpr int NN = 50000;   // nodes
static constexpr int NE = 800000;  // edges
static constexpr int NG = 512;     // graphs

__global__ void zero_kernel(float* __restrict__ p, int n) {
    int i = blockIdx.x * blockDim.x + threadIdx.x;
    if (i < n) p[i] = 0.f;
}

__global__ void deg_kernel(const int* __restrict__ dst, const float* __restrict__ ew,
                           float* __restrict__ deg) {
    int e = blockIdx.x * blockDim.x + threadIdx.x;
    if (e < NE) atomicAdd(&deg[dst[e]], ew[e]);
}

__global__ void dinv_kernel(const float* __restrict__ deg, float* __restrict__ dinv) {
    int i = blockIdx.x * blockDim.x + threadIdx.x;
    if (i < NN) {
        float d = deg[i] + 1.0f;  // + self-loop weight 1
        dinv[i] = (d > 0.f) ? (1.0f / sqrtf(d)) : 0.f;
    }
}

// X [NN,K] @ W [K,64] -> out [NN,64]. One block = 4 rows x 64 cols; W staged in LDS.
template <int K>
__global__ __launch_bounds__(256) void gemm_kernel(const float* __restrict__ X,
                                                   const float* __restrict__ W,
                                                   float* __restrict__ out) {
    __shared__ float Wl[K * 64];
    for (int i = threadIdx.x; i < K * 64; i += 256) Wl[i] = W[i];
    __syncthreads();
    int row = blockIdx.x * 4 + (threadIdx.x >> 6);
    int col = threadIdx.x & 63;
    if (row >= NN) return;
    const float* xr = X + (long long)row * K;
    float acc = 0.f;
#pragma unroll 16
    for (int k = 0; k < K; ++k) acc = fmaf(xr[k], Wl[k * 64 + col], acc);
    out[row * 64 + col] = acc;
}

// out[i,c] = dinv[i]^2 * xw[i,c] + b[c]   (self-loop message + bias, full overwrite)
__global__ void init_kernel(const float* __restrict__ xw, const float* __restrict__ dinv,
                            const float* __restrict__ b, float* __restrict__ out) {
    int t = blockIdx.x * blockDim.x + threadIdx.x;
    if (t >= NN * 64) return;
    int i = t >> 6, c = t & 63;
    float di = dinv[i];
    out[t] = di * di * xw[t] + b[c];
}

// 64 threads per edge (one channel each): out[dst] += dinv[s]*ew*dinv[d] * xw[src]
__global__ void edge_agg_kernel(const int* __restrict__ src, const int* __restrict__ dst,
                                const float* __restrict__ ew, const float* __restrict__ dinv,
                                const float* __restrict__ xw, float* __restrict__ out) {
    long long t = (long long)blockIdx.x * blockDim.x + threadIdx.x;
    int e = (int)(t >> 6), c = (int)(t & 63);
    if (e >= NE) return;
    int s = src[e], d = dst[e];
    float coef = dinv[s] * ew[e] * dinv[d];
    atomicAdd(&out[d * 64 + c], coef * xw[s * 64 + c]);
}

__global__ void relu_kernel(float* __restrict__ p, int n) {
    int i = blockIdx.x * blockDim.x + threadIdx.x;
    if (i < n) p[i] = fmaxf(p[i], 0.f);
}

__global__ void pool_kernel(const int* __restrict__ batch, const float* __restrict__ h,
                            float* __restrict__ sums, int* __restrict__ cnt) {
    int t = blockIdx.x * blockDim.x + threadIdx.x;
    if (t >= NN * 64) return;
    int i = t >> 6, c = t & 63;
    int g = batch[i];
    atomicAdd(&sums[g * 64 + c], h[t]);
    if (c == 0) atomicAdd(&cnt[g], 1);
}

// per-graph head: pooled = sums/cnt; t1 = pooled@LW1+Lb1 [32]; out = t1@LW2+Lb2 [10]
__global__ __launch_bounds__(64) void head_kernel(const float* __restrict__ sums,
                                                  const int* __restrict__ cnt,
                                                  const float* __restrict__ LW1,
                                                  const float* __restrict__ Lb1,
                                                  const float* __restrict__ LW2,
                                                  const float* __restrict__ Lb2,
                                                  float* __restrict__ out) {
    __shared__ float p[64];
    __shared__ float t1[32];
    int g = blockIdx.x;
    int t = threadIdx.x;
    float c = fmaxf((float)cnt[g], 1.0f);
    p[t] = sums[g * 64 + t] / c;
    __syncthreads();
    if (t < 32) {
        float acc = Lb1[t];
#pragma unroll
        for (int k = 0; k < 64; ++k) acc = fmaf(p[k], LW1[k * 32 + t], acc);
        t1[t] = acc;
    }
    __syncthreads();
    if (t < 10) {
        float acc = Lb2[t];
#pragma unroll
        for (int j = 0; j < 32; ++j) acc = fmaf(t1[j], LW2[j * 10 + t], acc);
        out[g * 10 + t] = acc;
    }
}

extern "C" void kernel_launch(void* const* d_in, const int* in_sizes, int n_in,
                              void* d_out, int out_size, void* d_ws, size_t ws_size,
                              hipStream_t stream) {
    const float* x     = (const float*)d_in[0];
    const int*   ei    = (const int*)d_in[1];   // [2, NE] int32
    const float* ew    = (const float*)d_in[2];
    const int*   batch = (const int*)d_in[3];
    const float* W1    = (const float*)d_in[4];
    const float* b1    = (const float*)d_in[5];
    const float* W2    = (const float*)d_in[6];
    const float* b2    = (const float*)d_in[7];
    const float* LW1   = (const float*)d_in[8];
    const float* Lb1   = (const float*)d_in[9];
    const float* LW2   = (const float*)d_in[10];
    const float* Lb2   = (const float*)d_in[11];

    const int* src = ei;
    const int* dst = ei + NE;

    // workspace layout (floats)
    float* ws   = (float*)d_ws;
    float* deg  = ws;                  // 50000
    float* sums = ws + 50048;          // 512*64 = 32768
    int*   cnt  = (int*)(ws + 82816);  // 512
    float* dinv = ws + 83328;          // 50000
    float* bufA = ws + 133376;         // 3.2M  (xw1, later xw2)
    float* bufB = ws + 3333376;        // 3.2M  (out1/h1, later out2/h2)
    // total ~6.54M floats = 26.2 MB

    // zero deg + sums + cnt in one pass
    zero_kernel<<<(83328 + 255) / 256, 256, 0, stream>>>(ws, 83328);

    // degree + dinv (shared between both conv layers)
    deg_kernel<<<(NE + 255) / 256, 256, 0, stream>>>(dst, ew, deg);
    dinv_kernel<<<(NN + 255) / 256, 256, 0, stream>>>(deg, dinv);

    // ---- layer 1 ----
    gemm_kernel<128><<<(NN + 3) / 4, 256, 0, stream>>>(x, W1, bufA);
    init_kernel<<<(NN * 64 + 255) / 256, 256, 0, stream>>>(bufA, dinv, b1, bufB);
    edge_agg_kernel<<<(NE * 64) / 256, 256, 0, stream>>>(src, dst, ew, dinv, bufA, bufB);
    relu_kernel<<<(NN * 64 + 255) / 256, 256, 0, stream>>>(bufB, NN * 64);

    // ---- layer 2 ----
    gemm_kernel<64><<<(NN + 3) / 4, 256, 0, stream>>>(bufB, W2, bufA);
    init_kernel<<<(NN * 64 + 255) / 256, 256, 0, stream>>>(bufA, dinv, b2, bufB);
    edge_agg_kernel<<<(NE * 64) / 256, 256, 0, stream>>>(src, dst, ew, dinv, bufA, bufB);

    // ---- pool + head ----
    pool_kernel<<<(NN * 64 + 255) / 256, 256, 0, stream>>>(batch, bufB, sums, cnt);
    head_kernel<<<NG, 64, 0, stream>>>(sums, cnt, LW1, Lb1, LW2, Lb2, (float*)d_out);
}

// Round 2
// 452.070 us; speedup vs baseline: 1.5036x; 1.5036x over previous
//
#include <hip/hip_runtime.h>

static constexpr int NN = 50000;   // nodes
static constexpr int NE = 800000;  // edges
static constexpr int NG = 512;     // graphs

// ---------------- utility ----------------

__global__ void zero_kernel(float* __restrict__ p, int n) {
    int i = blockIdx.x * blockDim.x + threadIdx.x;
    if (i < n) p[i] = 0.f;
}

// deg[d] += ew  and  count[d] += 1 per edge (CSR histogram + normalization degree)
__global__ void hist_kernel(const int* __restrict__ dst, const float* __restrict__ ew,
                            float* __restrict__ deg, int* __restrict__ count) {
    int e = blockIdx.x * blockDim.x + threadIdx.x;
    if (e < NE) {
        int d = dst[e];
        atomicAdd(&deg[d], ew[e]);
        atomicAdd(&count[d], 1);
    }
}

__global__ void dinv_kernel(const float* __restrict__ deg, float* __restrict__ dinv) {
    int i = blockIdx.x * blockDim.x + threadIdx.x;
    if (i < NN) {
        float d = deg[i] + 1.0f;  // + self-loop weight 1 (always > 0)
        dinv[i] = 1.0f / sqrtf(d);
    }
}

// Exclusive scan of count[NN] -> rowptr[NN+1]; single block of 1024 threads,
// wave-shuffle scan + cross-wave LDS, ~49 chunks.
__global__ __launch_bounds__(1024) void scan_kernel(const int* __restrict__ count,
                                                    int* __restrict__ rowptr) {
    __shared__ int wtot[16];
    __shared__ int carry_s;
    int t = threadIdx.x;
    int lane = t & 63, wid = t >> 6;
    if (t == 0) { carry_s = 0; rowptr[0] = 0; }
    __syncthreads();
    for (int base = 0; base < NN; base += 1024) {
        int idx = base + t;
        int v = (idx < NN) ? count[idx] : 0;
        int inc = v;
#pragma unroll
        for (int off = 1; off < 64; off <<= 1) {
            int n = __shfl_up(inc, (unsigned)off, 64);
            if (lane >= off) inc += n;
        }
        if (lane == 63) wtot[wid] = inc;
        __syncthreads();
        if (wid == 0) {
            int wv = (lane < 16) ? wtot[lane] : 0;
#pragma unroll
            for (int off = 1; off < 16; off <<= 1) {
                int n = __shfl_up(wv, (unsigned)off, 64);
                if (lane >= off) wv += n;
            }
            if (lane < 16) wtot[lane] = wv;  // inclusive wave totals
        }
        __syncthreads();
        int woff = (wid > 0) ? wtot[wid - 1] : 0;
        int carry = carry_s;
        int incl = carry + woff + inc;
        if (idx < NN) rowptr[idx + 1] = incl;
        __syncthreads();
        if (t == 1023) carry_s = incl;
        __syncthreads();
    }
}

// Scatter edges into CSR slots: epack[pos] = (src, coef) with coef = dinv[s]*ew*dinv[d]
__global__ void scatter_kernel(const int* __restrict__ src, const int* __restrict__ dst,
                               const float* __restrict__ ew, const float* __restrict__ dinv,
                               const int* __restrict__ rowptr, int* __restrict__ fill,
                               int2* __restrict__ epack) {
    int e = blockIdx.x * blockDim.x + threadIdx.x;
    if (e >= NE) return;
    int s = src[e], d = dst[e];
    int pos = rowptr[d] + atomicAdd(&fill[d], 1);
    float coef = dinv[s] * ew[e] * dinv[d];
    epack[pos] = make_int2(s, __float_as_int(coef));
}

// graph segment boundaries from the SORTED batch array
__global__ void bounds_kernel(const int* __restrict__ batch, int* __restrict__ gbeg,
                              int* __restrict__ gend) {
    int i = blockIdx.x * blockDim.x + threadIdx.x;
    if (i >= NN) return;
    int g = batch[i];
    if (i == 0 || batch[i - 1] != g) gbeg[g] = i;
    if (i == NN - 1 || batch[i + 1] != g) gend[g] = i + 1;
}

// ---------------- dense GEMM: X [NN,K] @ W [K,64] -> out [NN,64] ----------------
// 4 rows per thread, W staged in LDS, float4 x-loads. 16 rows per 256-thread block.
template <int K>
__global__ __launch_bounds__(256) void gemm_kernel(const float* __restrict__ X,
                                                   const float* __restrict__ W,
                                                   float* __restrict__ out) {
    __shared__ float Wl[K * 64];
    for (int i = threadIdx.x; i < K * 64; i += 256) Wl[i] = W[i];
    __syncthreads();
    int col = threadIdx.x & 63;
    int wid = threadIdx.x >> 6;
    int row0 = blockIdx.x * 16 + wid * 4;       // NN % 16 == 0, no bounds needed
    const float* x0 = X + (long long)row0 * K;
    float a0 = 0.f, a1 = 0.f, a2 = 0.f, a3 = 0.f;
#pragma unroll 4
    for (int k4 = 0; k4 < K / 4; ++k4) {
        float4 xv0 = ((const float4*)x0)[k4];
        float4 xv1 = ((const float4*)(x0 + K))[k4];
        float4 xv2 = ((const float4*)(x0 + 2 * K))[k4];
        float4 xv3 = ((const float4*)(x0 + 3 * K))[k4];
        int kb = k4 * 4;
        float w0 = Wl[(kb + 0) * 64 + col];
        float w1 = Wl[(kb + 1) * 64 + col];
        float w2 = Wl[(kb + 2) * 64 + col];
        float w3 = Wl[(kb + 3) * 64 + col];
        a0 = fmaf(xv0.x, w0, fmaf(xv0.y, w1, fmaf(xv0.z, w2, fmaf(xv0.w, w3, a0))));
        a1 = fmaf(xv1.x, w0, fmaf(xv1.y, w1, fmaf(xv1.z, w2, fmaf(xv1.w, w3, a1))));
        a2 = fmaf(xv2.x, w0, fmaf(xv2.y, w1, fmaf(xv2.z, w2, fmaf(xv2.w, w3, a2))));
        a3 = fmaf(xv3.x, w0, fmaf(xv3.y, w1, fmaf(xv3.z, w2, fmaf(xv3.w, w3, a3))));
    }
    out[(row0 + 0) * 64 + col] = a0;
    out[(row0 + 1) * 64 + col] = a1;
    out[(row0 + 2) * 64 + col] = a2;
    out[(row0 + 3) * 64 + col] = a3;
}

// ---------------- CSR aggregation: one wave per dst node, lane = channel ----------------
// out[i,c] = bias[c] + dinv[i]^2*xw[i,c] + sum_j coef_j * xw[src_j, c]   (+ ReLU)
template <bool RELU>
__global__ __launch_bounds__(256) void agg_kernel(const float* __restrict__ xw,
                                                  const int* __restrict__ rowptr,
                                                  const int2* __restrict__ epack,
                                                  const float* __restrict__ dinv,
                                                  const float* __restrict__ bias,
                                                  float* __restrict__ out) {
    int node = blockIdx.x * 4 + (threadIdx.x >> 6);
    int c = threadIdx.x & 63;
    if (node >= NN) return;
    float di = dinv[node];
    float acc = fmaf(di * di, xw[node * 64 + c], bias[c]);
    int j = rowptr[node], end = rowptr[node + 1];
    for (; j + 1 < end; j += 2) {
        int2 p0 = epack[j];
        int2 p1 = epack[j + 1];
        acc = fmaf(__int_as_float(p0.y), xw[p0.x * 64 + c], acc);
        acc = fmaf(__int_as_float(p1.y), xw[p1.x * 64 + c], acc);
    }
    if (j < end) {
        int2 p0 = epack[j];
        acc = fmaf(__int_as_float(p0.y), xw[p0.x * 64 + c], acc);
    }
    if (RELU) acc = fmaxf(acc, 0.f);
    out[node * 64 + c] = acc;
}

// ---------------- fused mean-pool + MLP head: one wave per graph ----------------
__global__ __launch_bounds__(64) void poolhead_kernel(const float* __restrict__ h,
                                                      const int* __restrict__ gbeg,
                                                      const int* __restrict__ gend,
                                                      const float* __restrict__ LW1,
                                                      const float* __restrict__ Lb1,
                                                      const float* __restrict__ LW2,
                                                      const float* __restrict__ Lb2,
                                                      float* __restrict__ out) {
    __shared__ float p[64];
    __shared__ float t1[32];
    int g = blockIdx.x, t = threadIdx.x;
    int b = gbeg[g], e = gend[g];
    float acc = 0.f;
#pragma unroll 4
    for (int i = b; i < e; ++i) acc += h[i * 64 + t];
    float c = fmaxf((float)(e - b), 1.0f);
    p[t] = acc / c;
    __syncthreads();
    if (t < 32) {
        float a = Lb1[t];
#pragma unroll
        for (int k = 0; k < 64; ++k) a = fmaf(p[k], LW1[k * 32 + t], a);
        t1[t] = a;
    }
    __syncthreads();
    if (t < 10) {
        float a = Lb2[t];
#pragma unroll
        for (int j = 0; j < 32; ++j) a = fmaf(t1[j], LW2[j * 10 + t], a);
        out[g * 10 + t] = a;
    }
}

// ---------------- launch ----------------

extern "C" void kernel_launch(void* const* d_in, const int* in_sizes, int n_in,
                              void* d_out, int out_size, void* d_ws, size_t ws_size,
                              hipStream_t stream) {
    const float* x     = (const float*)d_in[0];
    const int*   ei    = (const int*)d_in[1];   // [2, NE]
    const float* ew    = (const float*)d_in[2];
    const int*   batch = (const int*)d_in[3];
    const float* W1    = (const float*)d_in[4];
    const float* b1    = (const float*)d_in[5];
    const float* W2    = (const float*)d_in[6];
    const float* b2    = (const float*)d_in[7];
    const float* LW1   = (const float*)d_in[8];
    const float* Lb1   = (const float*)d_in[9];
    const float* LW2   = (const float*)d_in[10];
    const float* Lb2   = (const float*)d_in[11];

    const int* src = ei;
    const int* dst = ei + NE;

    // workspace layout (4-byte elements)
    float* ws     = (float*)d_ws;
    float* deg    = ws;                        // [NN]        @ 0
    int*   count  = (int*)(ws + 50048);        // [NN]
    int*   fill   = (int*)(ws + 100096);       // [NN]
    int*   gbeg   = (int*)(ws + 150144);       // [NG]
    int*   gend   = (int*)(ws + 150656);       // [NG]
    // ---- zero range ends at 151168 ----
    float* dinv   = ws + 151168;               // [NN]
    int*   rowptr = (int*)(ws + 201216);       // [NN+1]
    int2*  epack  = (int2*)(ws + 252288);      // [NE] int2 (8B-aligned)
    float* bufA   = ws + 1852288;              // [NN*64]
    float* bufB   = ws + 5052288;              // [NN*64]
    // total 8252288 elems = 33.0 MB

    // zero deg + count + fill + gbeg + gend
    zero_kernel<<<(151168 + 255) / 256, 256, 0, stream>>>(ws, 151168);

    // CSR build + normalization (shared by both layers)
    hist_kernel<<<(NE + 255) / 256, 256, 0, stream>>>(dst, ew, deg, count);
    dinv_kernel<<<(NN + 255) / 256, 256, 0, stream>>>(deg, dinv);
    scan_kernel<<<1, 1024, 0, stream>>>(count, rowptr);
    scatter_kernel<<<(NE + 255) / 256, 256, 0, stream>>>(src, dst, ew, dinv, rowptr, fill, epack);
    bounds_kernel<<<(NN + 255) / 256, 256, 0, stream>>>(batch, gbeg, gend);

    // ---- layer 1 ----
    gemm_kernel<128><<<NN / 16, 256, 0, stream>>>(x, W1, bufA);
    agg_kernel<true><<<(NN + 3) / 4, 256, 0, stream>>>(bufA, rowptr, epack, dinv, b1, bufB);

    // ---- layer 2 ----
    gemm_kernel<64><<<NN / 16, 256, 0, stream>>>(bufB, W2, bufA);
    agg_kernel<false><<<(NN + 3) / 4, 256, 0, stream>>>(bufA, rowptr, epack, dinv, b2, bufB);

    // ---- pool + head ----
    poolhead_kernel<<<NG, 64, 0, stream>>>(bufB, gbeg, gend, LW1, Lb1, LW2, Lb2, (float*)d_out);
}

// Round 3
// 354.760 us; speedup vs baseline: 1.9160x; 1.2743x over previous
//
#include <hip/hip_runtime.h>

static constexpr int NN = 50000;   // nodes
static constexpr int NE = 800000;  // edges
static constexpr int NG = 512;     // graphs
static constexpr int NB = 196;     // scan blocks: 196*256 >= NN

// ---------------- utility ----------------

__global__ void zero_kernel(float* __restrict__ p, int n) {
    int i = blockIdx.x * blockDim.x + threadIdx.x;
    if (i < n) p[i] = 0.f;
}

// One 64-bit atomic per edge: count in [40:64), sum(ew) in 2^-20 fixed point in [0:40).
// Returned old count = this edge's rank within its dst group (free CSR fill counter).
__global__ void hist64_kernel(const int* __restrict__ dst, const float* __restrict__ ew,
                              unsigned long long* __restrict__ h, int* __restrict__ rank) {
    int e = blockIdx.x * blockDim.x + threadIdx.x;
    if (e >= NE) return;
    int d = dst[e];
    unsigned int fx = __float2uint_rn(ew[e] * 1048576.0f);
    unsigned long long pack = (1ULL << 40) | (unsigned long long)fx;
    unsigned long long old = atomicAdd(&h[d], pack);
    rank[e] = (int)(old >> 40);
}

__global__ void dinv_kernel(const unsigned long long* __restrict__ h,
                            float* __restrict__ dinv) {
    int i = blockIdx.x * blockDim.x + threadIdx.x;
    if (i < NN) {
        float deg = (float)(h[i] & ((1ULL << 40) - 1)) * (1.0f / 1048576.0f) + 1.0f;
        dinv[i] = 1.0f / sqrtf(deg);
    }
}

// ---------------- 3-phase exclusive scan of counts -> rowptr ----------------

__device__ __forceinline__ int block_scan_inclusive(int v, int* wtot) {
    int lane = threadIdx.x & 63, wid = threadIdx.x >> 6;
    int inc = v;
#pragma unroll
    for (int off = 1; off < 64; off <<= 1) {
        int n = __shfl_up(inc, (unsigned)off, 64);
        if (lane >= off) inc += n;
    }
    if (lane == 63) wtot[wid] = inc;
    __syncthreads();
    int add = 0;
    for (int w = 0; w < wid; ++w) add += wtot[w];
    return inc + add;
}

__global__ __launch_bounds__(256) void scanA_kernel(const unsigned long long* __restrict__ h,
                                                    int* __restrict__ partial) {
    int i = blockIdx.x * 256 + threadIdx.x;
    int v = (i < NN) ? (int)(h[i] >> 40) : 0;
    __shared__ int wsum[4];
    int lane = threadIdx.x & 63, wid = threadIdx.x >> 6;
#pragma unroll
    for (int off = 32; off > 0; off >>= 1) v += __shfl_down(v, (unsigned)off, 64);
    if (lane == 0) wsum[wid] = v;
    __syncthreads();
    if (threadIdx.x == 0) partial[blockIdx.x] = wsum[0] + wsum[1] + wsum[2] + wsum[3];
}

__global__ __launch_bounds__(256) void scanB_kernel(const int* __restrict__ partial,
                                                    int* __restrict__ poff) {
    __shared__ int wtot[4];
    int t = threadIdx.x;
    int v = (t < NB) ? partial[t] : 0;
    int incl = block_scan_inclusive(v, wtot);
    if (t < NB) poff[t] = incl - v;  // exclusive
}

__global__ __launch_bounds__(256) void scanC_kernel(const unsigned long long* __restrict__ h,
                                                    const int* __restrict__ poff,
                                                    int* __restrict__ rowptr) {
    __shared__ int wtot[4];
    int i = blockIdx.x * 256 + threadIdx.x;
    int v = (i < NN) ? (int)(h[i] >> 40) : 0;
    int incl = block_scan_inclusive(v, wtot);
    if (i < NN) rowptr[i + 1] = poff[blockIdx.x] + incl;
    if (i == 0) rowptr[0] = 0;
}

// Atomic-free scatter: pos = rowptr[d] + rank[e]; epack[pos] = (src, coef)
__global__ void scatter_kernel(const int* __restrict__ src, const int* __restrict__ dst,
                               const float* __restrict__ ew, const float* __restrict__ dinv,
                               const int* __restrict__ rowptr, const int* __restrict__ rank,
                               int2* __restrict__ epack) {
    int e = blockIdx.x * blockDim.x + threadIdx.x;
    if (e >= NE) return;
    int s = src[e], d = dst[e];
    int pos = rowptr[d] + rank[e];
    float coef = dinv[s] * ew[e] * dinv[d];
    epack[pos] = make_int2(s, __float_as_int(coef));
}

// graph segment boundaries from the SORTED batch array
__global__ void bounds_kernel(const int* __restrict__ batch, int* __restrict__ gbeg,
                              int* __restrict__ gend) {
    int i = blockIdx.x * blockDim.x + threadIdx.x;
    if (i >= NN) return;
    int g = batch[i];
    if (i == 0 || batch[i - 1] != g) gbeg[g] = i;
    if (i == NN - 1 || batch[i + 1] != g) gend[g] = i + 1;
}

// ---------------- dense GEMM: X [NN,K] @ W [K,64] -> out [NN,64] ----------------
template <int K>
__global__ __launch_bounds__(256) void gemm_kernel(const float* __restrict__ X,
                                                   const float* __restrict__ W,
                                                   float* __restrict__ out) {
    __shared__ float Wl[K * 64];
    for (int i = threadIdx.x; i < K * 64; i += 256) Wl[i] = W[i];
    __syncthreads();
    int col = threadIdx.x & 63;
    int wid = threadIdx.x >> 6;
    int row0 = blockIdx.x * 16 + wid * 4;       // NN % 16 == 0
    const float* x0 = X + (long long)row0 * K;
    float a0 = 0.f, a1 = 0.f, a2 = 0.f, a3 = 0.f;
#pragma unroll 4
    for (int k4 = 0; k4 < K / 4; ++k4) {
        float4 xv0 = ((const float4*)x0)[k4];
        float4 xv1 = ((const float4*)(x0 + K))[k4];
        float4 xv2 = ((const float4*)(x0 + 2 * K))[k4];
        float4 xv3 = ((const float4*)(x0 + 3 * K))[k4];
        int kb = k4 * 4;
        float w0 = Wl[(kb + 0) * 64 + col];
        float w1 = Wl[(kb + 1) * 64 + col];
        float w2 = Wl[(kb + 2) * 64 + col];
        float w3 = Wl[(kb + 3) * 64 + col];
        a0 = fmaf(xv0.x, w0, fmaf(xv0.y, w1, fmaf(xv0.z, w2, fmaf(xv0.w, w3, a0))));
        a1 = fmaf(xv1.x, w0, fmaf(xv1.y, w1, fmaf(xv1.z, w2, fmaf(xv1.w, w3, a1))));
        a2 = fmaf(xv2.x, w0, fmaf(xv2.y, w1, fmaf(xv2.z, w2, fmaf(xv2.w, w3, a2))));
        a3 = fmaf(xv3.x, w0, fmaf(xv3.y, w1, fmaf(xv3.z, w2, fmaf(xv3.w, w3, a3))));
    }
    out[(row0 + 0) * 64 + col] = a0;
    out[(row0 + 1) * 64 + col] = a1;
    out[(row0 + 2) * 64 + col] = a2;
    out[(row0 + 3) * 64 + col] = a3;
}

// ---------------- CSR aggregation: one wave per dst node, lane = channel ----------------
template <bool RELU>
__global__ __launch_bounds__(256) void agg_kernel(const float* __restrict__ xw,
                                                  const int* __restrict__ rowptr,
                                                  const int2* __restrict__ epack,
                                                  const float* __restrict__ dinv,
                                                  const float* __restrict__ bias,
                                                  float* __restrict__ out) {
    int node = blockIdx.x * 4 + (threadIdx.x >> 6);
    int c = threadIdx.x & 63;
    if (node >= NN) return;
    float di = dinv[node];
    float acc = fmaf(di * di, xw[node * 64 + c], bias[c]);
    int j = rowptr[node], end = rowptr[node + 1];
    for (; j + 1 < end; j += 2) {
        int2 p0 = epack[j];
        int2 p1 = epack[j + 1];
        acc = fmaf(__int_as_float(p0.y), xw[p0.x * 64 + c], acc);
        acc = fmaf(__int_as_float(p1.y), xw[p1.x * 64 + c], acc);
    }
    if (j < end) {
        int2 p0 = epack[j];
        acc = fmaf(__int_as_float(p0.y), xw[p0.x * 64 + c], acc);
    }
    if (RELU) acc = fmaxf(acc, 0.f);
    out[node * 64 + c] = acc;
}

// ---------------- fused mean-pool + MLP head: 4 waves per graph ----------------
__global__ __launch_bounds__(256) void poolhead_kernel(const float* __restrict__ h,
                                                       const int* __restrict__ gbeg,
                                                       const int* __restrict__ gend,
                                                       const float* __restrict__ LW1,
                                                       const float* __restrict__ Lb1,
                                                       const float* __restrict__ LW2,
                                                       const float* __restrict__ Lb2,
                                                       float* __restrict__ out) {
    __shared__ float pp[4][64];
    __shared__ float p[64];
    __shared__ float t1[32];
    int g = blockIdx.x, t = threadIdx.x;
    int lane = t & 63, wid = t >> 6;
    int b = gbeg[g], e = gend[g];
    float acc = 0.f;
    for (int i = b + wid; i < e; i += 4) acc += h[i * 64 + lane];
    pp[wid][lane] = acc;
    __syncthreads();
    if (t < 64) {
        float s = pp[0][t] + pp[1][t] + pp[2][t] + pp[3][t];
        p[t] = s / fmaxf((float)(e - b), 1.0f);
    }
    __syncthreads();
    if (t < 32) {
        float a = Lb1[t];
#pragma unroll
        for (int k = 0; k < 64; ++k) a = fmaf(p[k], LW1[k * 32 + t], a);
        t1[t] = a;
    }
    __syncthreads();
    if (t < 10) {
        float a = Lb2[t];
#pragma unroll
        for (int j = 0; j < 32; ++j) a = fmaf(t1[j], LW2[j * 10 + t], a);
        out[g * 10 + t] = a;
    }
}

// ---------------- launch ----------------

extern "C" void kernel_launch(void* const* d_in, const int* in_sizes, int n_in,
                              void* d_out, int out_size, void* d_ws, size_t ws_size,
                              hipStream_t stream) {
    const float* x     = (const float*)d_in[0];
    const int*   ei    = (const int*)d_in[1];   // [2, NE]
    const float* ew    = (const float*)d_in[2];
    const int*   batch = (const int*)d_in[3];
    const float* W1    = (const float*)d_in[4];
    const float* b1    = (const float*)d_in[5];
    const float* W2    = (const float*)d_in[6];
    const float* b2    = (const float*)d_in[7];
    const float* LW1   = (const float*)d_in[8];
    const float* Lb1   = (const float*)d_in[9];
    const float* LW2   = (const float*)d_in[10];
    const float* Lb2   = (const float*)d_in[11];

    const int* src = ei;
    const int* dst = ei + NE;

    // workspace layout (4-byte units)
    float* ws = (float*)d_ws;
    unsigned long long* h64 = (unsigned long long*)ws;  // [NN] ull @ 0 .. 100096
    int*   gbeg   = (int*)(ws + 100096);       // [NG]
    int*   gend   = (int*)(ws + 100608);       // [NG]
    // ---- zero range ends at 101120 ----
    float* dinv   = ws + 101120;               // [NN]      -> 151168
    int*   rowptr = (int*)(ws + 151168);       // [NN+1]    -> 201216
    int*   partial  = (int*)(ws + 201216);     // [NB]      -> 201472
    int*   poff     = (int*)(ws + 201472);     // [NB]      -> 201728
    int2*  epack  = (int2*)(ws + 201728);      // [NE] int2 -> 1801728 (8B aligned)
    float* bufA   = ws + 1801728;              // [NN*64]   -> 5001728
    float* bufB   = ws + 5001728;              // [NN*64]   -> 8201728  (32.8 MB total)
    // rank is dead after scatter; alias it into bufB (first written by agg1, after scatter)
    int*   rank   = (int*)(ws + 5001728);      // [NE]

    // zero h64 + gbeg + gend
    zero_kernel<<<(101120 + 255) / 256, 256, 0, stream>>>(ws, 101120);

    // CSR build + normalization (1 atomic per edge total)
    hist64_kernel<<<(NE + 255) / 256, 256, 0, stream>>>(dst, ew, h64, rank);
    dinv_kernel<<<NB, 256, 0, stream>>>(h64, dinv);
    scanA_kernel<<<NB, 256, 0, stream>>>(h64, partial);
    scanB_kernel<<<1, 256, 0, stream>>>(partial, poff);
    scanC_kernel<<<NB, 256, 0, stream>>>(h64, poff, rowptr);
    scatter_kernel<<<(NE + 255) / 256, 256, 0, stream>>>(src, dst, ew, dinv, rowptr, rank, epack);
    bounds_kernel<<<NB, 256, 0, stream>>>(batch, gbeg, gend);

    // ---- layer 1 ----
    gemm_kernel<128><<<NN / 16, 256, 0, stream>>>(x, W1, bufA);
    agg_kernel<true><<<(NN + 3) / 4, 256, 0, stream>>>(bufA, rowptr, epack, dinv, b1, bufB);

    // ---- layer 2 ----
    gemm_kernel<64><<<NN / 16, 256, 0, stream>>>(bufB, W2, bufA);
    agg_kernel<false><<<(NN + 3) / 4, 256, 0, stream>>>(bufA, rowptr, epack, dinv, b2, bufB);

    // ---- pool + head ----
    poolhead_kernel<<<NG, 256, 0, stream>>>(bufB, gbeg, gend, LW1, Lb1, LW2, Lb2, (float*)d_out);
}

// Round 4
// 275.934 us; speedup vs baseline: 2.4634x; 1.2857x over previous
//
#include <hip/hip_runtime.h>
#include <hip/hip_bf16.h>

static constexpr int NN = 50000;   // nodes
static constexpr int NE = 800000;  // edges
static constexpr int NG = 512;     // graphs
static constexpr int NB = 196;     // 196*256 >= NN

// ---------------- utility ----------------

__global__ void zero_kernel(float* __restrict__ p, int n) {
    int i = blockIdx.x * blockDim.x + threadIdx.x;
    if (i < n) p[i] = 0.f;
}

// One 64-bit atomic per edge: count in [40:64), sum(ew) in 2^-20 fixed point in [0:40).
// Returned old count = this edge's rank within its dst group (free CSR fill counter).
__global__ void hist64_kernel(const int* __restrict__ dst, const float* __restrict__ ew,
                              unsigned long long* __restrict__ h, int* __restrict__ rank) {
    int e = blockIdx.x * blockDim.x + threadIdx.x;
    if (e >= NE) return;
    int d = dst[e];
    unsigned int fx = __float2uint_rn(ew[e] * 1048576.0f);
    unsigned long long pack = (1ULL << 40) | (unsigned long long)fx;
    unsigned long long old = atomicAdd(&h[d], pack);
    rank[e] = (int)(old >> 40);
}

__global__ void dinv_kernel(const unsigned long long* __restrict__ h,
                            float* __restrict__ dinv) {
    int i = blockIdx.x * blockDim.x + threadIdx.x;
    if (i < NN) {
        float deg = (float)(h[i] & ((1ULL << 40) - 1)) * (1.0f / 1048576.0f) + 1.0f;
        dinv[i] = 1.0f / sqrtf(deg);
    }
}

// ---------------- 3-phase exclusive scan of counts -> rowptr ----------------

__device__ __forceinline__ int block_scan_inclusive(int v, int* wtot) {
    int lane = threadIdx.x & 63, wid = threadIdx.x >> 6;
    int inc = v;
#pragma unroll
    for (int off = 1; off < 64; off <<= 1) {
        int n = __shfl_up(inc, (unsigned)off, 64);
        if (lane >= off) inc += n;
    }
    if (lane == 63) wtot[wid] = inc;
    __syncthreads();
    int add = 0;
    for (int w = 0; w < wid; ++w) add += wtot[w];
    return inc + add;
}

__global__ __launch_bounds__(256) void scanA_kernel(const unsigned long long* __restrict__ h,
                                                    int* __restrict__ partial) {
    int i = blockIdx.x * 256 + threadIdx.x;
    int v = (i < NN) ? (int)(h[i] >> 40) : 0;
    __shared__ int wsum[4];
    int lane = threadIdx.x & 63, wid = threadIdx.x >> 6;
#pragma unroll
    for (int off = 32; off > 0; off >>= 1) v += __shfl_down(v, (unsigned)off, 64);
    if (lane == 0) wsum[wid] = v;
    __syncthreads();
    if (threadIdx.x == 0) partial[blockIdx.x] = wsum[0] + wsum[1] + wsum[2] + wsum[3];
}

__global__ __launch_bounds__(256) void scanB_kernel(const int* __restrict__ partial,
                                                    int* __restrict__ poff) {
    __shared__ int wtot[4];
    int t = threadIdx.x;
    int v = (t < NB) ? partial[t] : 0;
    int incl = block_scan_inclusive(v, wtot);
    if (t < NB) poff[t] = incl - v;  // exclusive
}

__global__ __launch_bounds__(256) void scanC_kernel(const unsigned long long* __restrict__ h,
                                                    const int* __restrict__ poff,
                                                    int* __restrict__ rowptr) {
    __shared__ int wtot[4];
    int i = blockIdx.x * 256 + threadIdx.x;
    int v = (i < NN) ? (int)(h[i] >> 40) : 0;
    int incl = block_scan_inclusive(v, wtot);
    if (i < NN) rowptr[i + 1] = poff[blockIdx.x] + incl;
    if (i == 0) rowptr[0] = 0;
}

// Atomic-free scatter: pos = rowptr[d] + rank[e]; epack[pos] = (src, coef)
__global__ void scatter_kernel(const int* __restrict__ src, const int* __restrict__ dst,
                               const float* __restrict__ ew, const float* __restrict__ dinv,
                               const int* __restrict__ rowptr, const int* __restrict__ rank,
                               int2* __restrict__ epack) {
    int e = blockIdx.x * blockDim.x + threadIdx.x;
    if (e >= NE) return;
    int s = src[e], d = dst[e];
    int pos = rowptr[d] + rank[e];
    float coef = dinv[s] * ew[e] * dinv[d];
    epack[pos] = make_int2(s, __float_as_int(coef));
}

// graph segment boundaries from the SORTED batch array
__global__ void bounds_kernel(const int* __restrict__ batch, int* __restrict__ gbeg,
                              int* __restrict__ gend) {
    int i = blockIdx.x * blockDim.x + threadIdx.x;
    if (i >= NN) return;
    int g = batch[i];
    if (i == 0 || batch[i - 1] != g) gbeg[g] = i;
    if (i == NN - 1 || batch[i + 1] != g) gend[g] = i + 1;
}

// ---------------- dense GEMM: X [NN,K] fp32 @ W [K,64] fp32 -> out [NN,64] bf16 ----------------
// 64 rows/block, LDS-staged X (64-k chunks) + full W, 16x16 threads, 4x4 register tile.
template <int K>
__global__ __launch_bounds__(256) void gemm_kernel(const float* __restrict__ X,
                                                   const float* __restrict__ W,
                                                   ushort* __restrict__ out) {
    __shared__ float Xs[64][68];       // 64 rows x 64 k, stride 68 (2-way conflicts only = free)
    __shared__ float Ws[K][64];
    // stage W (K*64 floats = K*16 float4)
    for (int i = threadIdx.x; i < K * 16; i += 256)
        ((float4*)Ws)[i] = ((const float4*)W)[i];
    int tx = threadIdx.x & 15, ty = threadIdx.x >> 4;
    int row0 = blockIdx.x * 64;
    float acc[4][4] = {};
    for (int kb = 0; kb < K; kb += 64) {
        __syncthreads();
        // stage X chunk: 64 rows x 64 k = 1024 float4, coalesced
        for (int i = threadIdx.x; i < 1024; i += 256) {
            int r = i >> 4, k4 = i & 15;
            int gr = row0 + r; if (gr >= NN) gr = NN - 1;
            float4 v = *(const float4*)(X + (long long)gr * K + kb + k4 * 4);
            *(float4*)&Xs[r][k4 * 4] = v;
        }
        __syncthreads();
#pragma unroll 16
        for (int k = 0; k < 64; ++k) {
            float4 wv = *(const float4*)&Ws[kb + k][tx * 4];
            float x0 = Xs[ty * 4 + 0][k];
            float x1 = Xs[ty * 4 + 1][k];
            float x2 = Xs[ty * 4 + 2][k];
            float x3 = Xs[ty * 4 + 3][k];
            acc[0][0] = fmaf(x0, wv.x, acc[0][0]); acc[0][1] = fmaf(x0, wv.y, acc[0][1]);
            acc[0][2] = fmaf(x0, wv.z, acc[0][2]); acc[0][3] = fmaf(x0, wv.w, acc[0][3]);
            acc[1][0] = fmaf(x1, wv.x, acc[1][0]); acc[1][1] = fmaf(x1, wv.y, acc[1][1]);
            acc[1][2] = fmaf(x1, wv.z, acc[1][2]); acc[1][3] = fmaf(x1, wv.w, acc[1][3]);
            acc[2][0] = fmaf(x2, wv.x, acc[2][0]); acc[2][1] = fmaf(x2, wv.y, acc[2][1]);
            acc[2][2] = fmaf(x2, wv.z, acc[2][2]); acc[2][3] = fmaf(x2, wv.w, acc[2][3]);
            acc[3][0] = fmaf(x3, wv.x, acc[3][0]); acc[3][1] = fmaf(x3, wv.y, acc[3][1]);
            acc[3][2] = fmaf(x3, wv.z, acc[3][2]); acc[3][3] = fmaf(x3, wv.w, acc[3][3]);
        }
    }
    // store 4 rows x 4 cols as bf16 (ushort4 = 8B per row-segment, coalesced across tx)
#pragma unroll
    for (int j = 0; j < 4; ++j) {
        int r = row0 + ty * 4 + j;
        if (r < NN) {
            ushort4 sv;
            sv.x = __hip_bfloat16_raw(__float2bfloat16(acc[j][0])).x;
            sv.y = __hip_bfloat16_raw(__float2bfloat16(acc[j][1])).x;
            sv.z = __hip_bfloat16_raw(__float2bfloat16(acc[j][2])).x;
            sv.w = __hip_bfloat16_raw(__float2bfloat16(acc[j][3])).x;
            *(ushort4*)(out + (long long)r * 64 + tx * 4) = sv;
        }
    }
}

// ---------------- CSR aggregation: one wave per dst node, lane = channel ----------------
// xw is bf16 (ushort bits); out fp32.
__device__ __forceinline__ float bf16_ld(const ushort* p) {
    return __uint_as_float((unsigned)(*p) << 16);
}

template <bool RELU>
__global__ __launch_bounds__(256) void agg_kernel(const ushort* __restrict__ xw,
                                                  const int* __restrict__ rowptr,
                                                  const int2* __restrict__ epack,
                                                  const float* __restrict__ dinv,
                                                  const float* __restrict__ bias,
                                                  float* __restrict__ out) {
    int node = blockIdx.x * 4 + (threadIdx.x >> 6);
    int c = threadIdx.x & 63;
    if (node >= NN) return;
    float di = dinv[node];
    float acc = fmaf(di * di, bf16_ld(xw + node * 64 + c), bias[c]);
    float acc2 = 0.f;
    int j = rowptr[node], end = rowptr[node + 1];
    for (; j + 3 < end; j += 4) {
        int2 p0 = epack[j];
        int2 p1 = epack[j + 1];
        int2 p2 = epack[j + 2];
        int2 p3 = epack[j + 3];
        float v0 = bf16_ld(xw + p0.x * 64 + c);
        float v1 = bf16_ld(xw + p1.x * 64 + c);
        float v2 = bf16_ld(xw + p2.x * 64 + c);
        float v3 = bf16_ld(xw + p3.x * 64 + c);
        acc  = fmaf(__int_as_float(p0.y), v0, acc);
        acc2 = fmaf(__int_as_float(p1.y), v1, acc2);
        acc  = fmaf(__int_as_float(p2.y), v2, acc);
        acc2 = fmaf(__int_as_float(p3.y), v3, acc2);
    }
    for (; j < end; ++j) {
        int2 p0 = epack[j];
        acc = fmaf(__int_as_float(p0.y), bf16_ld(xw + p0.x * 64 + c), acc);
    }
    acc += acc2;
    if (RELU) acc = fmaxf(acc, 0.f);
    out[node * 64 + c] = acc;
}

// ---------------- fused mean-pool + MLP head: 4 waves per graph ----------------
__global__ __launch_bounds__(256) void poolhead_kernel(const float* __restrict__ h,
                                                       const int* __restrict__ gbeg,
                                                       const int* __restrict__ gend,
                                                       const float* __restrict__ LW1,
                                                       const float* __restrict__ Lb1,
                                                       const float* __restrict__ LW2,
                                                       const float* __restrict__ Lb2,
                                                       float* __restrict__ out) {
    __shared__ float pp[4][64];
    __shared__ float p[64];
    __shared__ float t1[32];
    int g = blockIdx.x, t = threadIdx.x;
    int lane = t & 63, wid = t >> 6;
    int b = gbeg[g], e = gend[g];
    float acc = 0.f;
    for (int i = b + wid; i < e; i += 4) acc += h[i * 64 + lane];
    pp[wid][lane] = acc;
    __syncthreads();
    if (t < 64) {
        float s = pp[0][t] + pp[1][t] + pp[2][t] + pp[3][t];
        p[t] = s / fmaxf((float)(e - b), 1.0f);
    }
    __syncthreads();
    if (t < 32) {
        float a = Lb1[t];
#pragma unroll
        for (int k = 0; k < 64; ++k) a = fmaf(p[k], LW1[k * 32 + t], a);
        t1[t] = a;
    }
    __syncthreads();
    if (t < 10) {
        float a = Lb2[t];
#pragma unroll
        for (int j = 0; j < 32; ++j) a = fmaf(t1[j], LW2[j * 10 + t], a);
        out[g * 10 + t] = a;
    }
}

// ---------------- launch ----------------

extern "C" void kernel_launch(void* const* d_in, const int* in_sizes, int n_in,
                              void* d_out, int out_size, void* d_ws, size_t ws_size,
                              hipStream_t stream) {
    const float* x     = (const float*)d_in[0];
    const int*   ei    = (const int*)d_in[1];   // [2, NE]
    const float* ew    = (const float*)d_in[2];
    const int*   batch = (const int*)d_in[3];
    const float* W1    = (const float*)d_in[4];
    const float* b1    = (const float*)d_in[5];
    const float* W2    = (const float*)d_in[6];
    const float* b2    = (const float*)d_in[7];
    const float* LW1   = (const float*)d_in[8];
    const float* Lb1   = (const float*)d_in[9];
    const float* LW2   = (const float*)d_in[10];
    const float* Lb2   = (const float*)d_in[11];

    const int* src = ei;
    const int* dst = ei + NE;

    // workspace layout (4-byte units)
    float* ws = (float*)d_ws;
    unsigned long long* h64 = (unsigned long long*)ws;  // [NN] ull @ 0 .. 100096
    int*   gbeg   = (int*)(ws + 100096);       // [NG]
    int*   gend   = (int*)(ws + 100608);       // [NG]
    // ---- zero range ends at 101120 ----
    float* dinv   = ws + 101120;               // [NN]      -> 151168
    int*   rowptr = (int*)(ws + 151168);       // [NN+1]    -> 201216
    int*   partial  = (int*)(ws + 201216);     // [NB]      -> 201472
    int*   poff     = (int*)(ws + 201472);     // [NB]      -> 201728
    int2*  epack  = (int2*)(ws + 201728);      // [NE] int2 -> 1801728 (8B aligned)
    ushort* bufA  = (ushort*)(ws + 1801728);   // [NN*64] bf16 (uses half the region)
    float* bufB   = ws + 5001728;              // [NN*64] fp32 -> 8201728 (32.8 MB total)
    // rank is dead after scatter; alias it into bufB (first written by agg1, after scatter)
    int*   rank   = (int*)(ws + 5001728);      // [NE]

    // zero h64 + gbeg + gend
    zero_kernel<<<(101120 + 255) / 256, 256, 0, stream>>>(ws, 101120);

    // CSR build + normalization (1 atomic per edge total)
    hist64_kernel<<<(NE + 255) / 256, 256, 0, stream>>>(dst, ew, h64, rank);
    dinv_kernel<<<NB, 256, 0, stream>>>(h64, dinv);
    scanA_kernel<<<NB, 256, 0, stream>>>(h64, partial);
    scanB_kernel<<<1, 256, 0, stream>>>(partial, poff);
    scanC_kernel<<<NB, 256, 0, stream>>>(h64, poff, rowptr);
    scatter_kernel<<<(NE + 255) / 256, 256, 0, stream>>>(src, dst, ew, dinv, rowptr, rank, epack);
    bounds_kernel<<<NB, 256, 0, stream>>>(batch, gbeg, gend);

    // ---- layer 1 ----
    gemm_kernel<128><<<(NN + 63) / 64, 256, 0, stream>>>(x, W1, bufA);
    agg_kernel<true><<<(NN + 3) / 4, 256, 0, stream>>>(bufA, rowptr, epack, dinv, b1, bufB);

    // ---- layer 2 ----
    gemm_kernel<64><<<(NN + 63) / 64, 256, 0, stream>>>(bufB, W2, bufA);
    agg_kernel<false><<<(NN + 3) / 4, 256, 0, stream>>>(bufA, rowptr, epack, dinv, b2, bufB);

    // ---- pool + head ----
    poolhead_kernel<<<NG, 256, 0, stream>>>(bufB, gbeg, gend, LW1, Lb1, LW2, Lb2, (float*)d_out);
}

// Round 5
// 264.109 us; speedup vs baseline: 2.5737x; 1.0448x over previous
//
#include <hip/hip_runtime.h>
#include <hip/hip_bf16.h>

static constexpr int NN = 50000;   // nodes
static constexpr int NE = 800000;  // edges
static constexpr int NG = 512;     // graphs
static constexpr int NB = 196;     // 196*256 >= NN

__device__ __forceinline__ float bfu(ushort u) {
    return __uint_as_float((unsigned)u << 16);
}
__device__ __forceinline__ ushort fbf(float f) {
    return __hip_bfloat16_raw(__float2bfloat16(f)).x;
}

// ---------------- utility ----------------

__global__ void zero_kernel(float* __restrict__ p, int n) {
    int i = blockIdx.x * blockDim.x + threadIdx.x;
    if (i < n) p[i] = 0.f;
}

// One 64-bit atomic per edge: count in [40:64), sum(ew) in 2^-20 fixed point in [0:40).
// Returned old count = this edge's rank within its dst group (free CSR fill counter).
__global__ void hist64_kernel(const int* __restrict__ dst, const float* __restrict__ ew,
                              unsigned long long* __restrict__ h, int* __restrict__ rank) {
    int e = blockIdx.x * blockDim.x + threadIdx.x;
    if (e >= NE) return;
    int d = dst[e];
    unsigned int fx = __float2uint_rn(ew[e] * 1048576.0f);
    unsigned long long pack = (1ULL << 40) | (unsigned long long)fx;
    unsigned long long old = atomicAdd(&h[d], pack);
    rank[e] = (int)(old >> 40);
}

// fused: dinv computation + per-block count reduction (scan phase A)
__global__ __launch_bounds__(256) void dinv_scanA_kernel(const unsigned long long* __restrict__ h,
                                                         float* __restrict__ dinv,
                                                         int* __restrict__ partial) {
    int i = blockIdx.x * 256 + threadIdx.x;
    int cnt = 0;
    if (i < NN) {
        unsigned long long v = h[i];
        cnt = (int)(v >> 40);
        float deg = (float)(v & ((1ULL << 40) - 1)) * (1.0f / 1048576.0f) + 1.0f;
        dinv[i] = 1.0f / sqrtf(deg);
    }
    __shared__ int wsum[4];
    int lane = threadIdx.x & 63, wid = threadIdx.x >> 6;
    int v = cnt;
#pragma unroll
    for (int off = 32; off > 0; off >>= 1) v += __shfl_down(v, (unsigned)off, 64);
    if (lane == 0) wsum[wid] = v;
    __syncthreads();
    if (threadIdx.x == 0) partial[blockIdx.x] = wsum[0] + wsum[1] + wsum[2] + wsum[3];
}

__device__ __forceinline__ int block_scan_inclusive(int v, int* wtot) {
    int lane = threadIdx.x & 63, wid = threadIdx.x >> 6;
    int inc = v;
#pragma unroll
    for (int off = 1; off < 64; off <<= 1) {
        int n = __shfl_up(inc, (unsigned)off, 64);
        if (lane >= off) inc += n;
    }
    if (lane == 63) wtot[wid] = inc;
    __syncthreads();
    int add = 0;
    for (int w = 0; w < wid; ++w) add += wtot[w];
    return inc + add;
}

__global__ __launch_bounds__(256) void scanB_kernel(const int* __restrict__ partial,
                                                    int* __restrict__ poff) {
    __shared__ int wtot[4];
    int t = threadIdx.x;
    int v = (t < NB) ? partial[t] : 0;
    int incl = block_scan_inclusive(v, wtot);
    if (t < NB) poff[t] = incl - v;  // exclusive
}

// fused: rowptr finalize + graph segment bounds from SORTED batch
__global__ __launch_bounds__(256) void scanC_bounds_kernel(const unsigned long long* __restrict__ h,
                                                           const int* __restrict__ poff,
                                                           int* __restrict__ rowptr,
                                                           const int* __restrict__ batch,
                                                           int* __restrict__ gbeg,
                                                           int* __restrict__ gend) {
    __shared__ int wtot[4];
    int i = blockIdx.x * 256 + threadIdx.x;
    int v = (i < NN) ? (int)(h[i] >> 40) : 0;
    int incl = block_scan_inclusive(v, wtot);
    if (i < NN) {
        rowptr[i + 1] = poff[blockIdx.x] + incl;
        int g = batch[i];
        if (i == 0 || batch[i - 1] != g) gbeg[g] = i;
        if (i == NN - 1 || batch[i + 1] != g) gend[g] = i + 1;
    }
    if (i == 0) rowptr[0] = 0;
}

// Atomic-free scatter: pos = rowptr[d] + rank[e]; epack[pos] = (src, dinv[s]*ew)
// (dinv[d] is factored out -- applied once per node in agg)
__global__ void scatter_kernel(const int* __restrict__ src, const int* __restrict__ dst,
                               const float* __restrict__ ew, const float* __restrict__ dinv,
                               const int* __restrict__ rowptr, const int* __restrict__ rank,
                               int2* __restrict__ epack) {
    int e = blockIdx.x * blockDim.x + threadIdx.x;
    if (e >= NE) return;
    int s = src[e], d = dst[e];
    int pos = rowptr[d] + rank[e];
    float coef = dinv[s] * ew[e];
    epack[pos] = make_int2(s, __float_as_int(coef));
}

// ---------------- dense GEMM: X [NN,K] @ W [K,64] -> out [NN,64] bf16 ----------------
// 64 rows/block, LDS-staged X (64-k chunks) + full W, 16x16 threads, 4x4 register tile.
// BF16IN: X is bf16 (ushort bits), staged with widening to fp32 in LDS.
template <int K, bool BF16IN>
__global__ __launch_bounds__(256) void gemm_kernel(const void* __restrict__ Xv,
                                                   const float* __restrict__ W,
                                                   ushort* __restrict__ out) {
    __shared__ float Xs[64][68];       // stride 68: 2-way conflicts only (free)
    __shared__ float Ws[K][64];
    for (int i = threadIdx.x; i < K * 16; i += 256)
        ((float4*)Ws)[i] = ((const float4*)W)[i];
    int tx = threadIdx.x & 15, ty = threadIdx.x >> 4;
    int row0 = blockIdx.x * 64;
    float acc[4][4] = {};
    for (int kb = 0; kb < K; kb += 64) {
        __syncthreads();
        if constexpr (BF16IN) {
            const ushort* X = (const ushort*)Xv;
            for (int i = threadIdx.x; i < 512; i += 256) {   // 64 rows x 8 groups of 8 ch
                int r = i >> 3, g = i & 7;
                int gr = row0 + r; if (gr >= NN) gr = NN - 1;
                uint4 v = *(const uint4*)(X + (long long)gr * K + kb + g * 8);
                float4 f0, f1;
                f0.x = __uint_as_float(v.x << 16); f0.y = __uint_as_float(v.x & 0xffff0000u);
                f0.z = __uint_as_float(v.y << 16); f0.w = __uint_as_float(v.y & 0xffff0000u);
                f1.x = __uint_as_float(v.z << 16); f1.y = __uint_as_float(v.z & 0xffff0000u);
                f1.z = __uint_as_float(v.w << 16); f1.w = __uint_as_float(v.w & 0xffff0000u);
                *(float4*)&Xs[r][g * 8] = f0;
                *(float4*)&Xs[r][g * 8 + 4] = f1;
            }
        } else {
            const float* X = (const float*)Xv;
            for (int i = threadIdx.x; i < 1024; i += 256) {  // 64 rows x 16 float4
                int r = i >> 4, k4 = i & 15;
                int gr = row0 + r; if (gr >= NN) gr = NN - 1;
                float4 v = *(const float4*)(X + (long long)gr * K + kb + k4 * 4);
                *(float4*)&Xs[r][k4 * 4] = v;
            }
        }
        __syncthreads();
#pragma unroll 16
        for (int k = 0; k < 64; ++k) {
            float4 wv = *(const float4*)&Ws[kb + k][tx * 4];
            float x0 = Xs[ty * 4 + 0][k];
            float x1 = Xs[ty * 4 + 1][k];
            float x2 = Xs[ty * 4 + 2][k];
            float x3 = Xs[ty * 4 + 3][k];
            acc[0][0] = fmaf(x0, wv.x, acc[0][0]); acc[0][1] = fmaf(x0, wv.y, acc[0][1]);
            acc[0][2] = fmaf(x0, wv.z, acc[0][2]); acc[0][3] = fmaf(x0, wv.w, acc[0][3]);
            acc[1][0] = fmaf(x1, wv.x, acc[1][0]); acc[1][1] = fmaf(x1, wv.y, acc[1][1]);
            acc[1][2] = fmaf(x1, wv.z, acc[1][2]); acc[1][3] = fmaf(x1, wv.w, acc[1][3]);
            acc[2][0] = fmaf(x2, wv.x, acc[2][0]); acc[2][1] = fmaf(x2, wv.y, acc[2][1]);
            acc[2][2] = fmaf(x2, wv.z, acc[2][2]); acc[2][3] = fmaf(x2, wv.w, acc[2][3]);
            acc[3][0] = fmaf(x3, wv.x, acc[3][0]); acc[3][1] = fmaf(x3, wv.y, acc[3][1]);
            acc[3][2] = fmaf(x3, wv.z, acc[3][2]); acc[3][3] = fmaf(x3, wv.w, acc[3][3]);
        }
    }
#pragma unroll
    for (int j = 0; j < 4; ++j) {
        int r = row0 + ty * 4 + j;
        if (r < NN) {
            ushort4 sv;
            sv.x = fbf(acc[j][0]); sv.y = fbf(acc[j][1]);
            sv.z = fbf(acc[j][2]); sv.w = fbf(acc[j][3]);
            *(ushort4*)(out + (long long)r * 64 + tx * 4) = sv;
        }
    }
}

// ---------------- CSR aggregation: one wave per node; 2 half-waves x 2 channels/lane ----
// out[i,:] = bias + dinv[i]^2*xw[i,:] + dinv[i] * sum_j (dinv[s]*ew)_j * xw[src_j,:]
template <bool RELU, typename OutT>
__global__ __launch_bounds__(256) void agg_kernel(const ushort* __restrict__ xw,
                                                  const int* __restrict__ rowptr,
                                                  const int2* __restrict__ epack,
                                                  const float* __restrict__ dinv,
                                                  const float* __restrict__ bias,
                                                  OutT* __restrict__ out) {
    int node = blockIdx.x * 4 + (threadIdx.x >> 6);
    if (node >= NN) return;
    int lane = threadIdx.x & 63;
    int half = lane >> 5;        // which edge of the pair this half-wave takes
    int c2 = lane & 31;          // channel pair: handles channels 2*c2, 2*c2+1
    int beg = rowptr[node], end = rowptr[node + 1];
    float a0 = 0.f, a1 = 0.f, b0 = 0.f, b1 = 0.f;
    int j = beg + half;
    for (; j + 2 < end; j += 4) {
        int2 pa = epack[j];
        int2 pb = epack[j + 2];
        ushort2 ua = *(const ushort2*)(xw + pa.x * 64 + 2 * c2);
        ushort2 ub = *(const ushort2*)(xw + pb.x * 64 + 2 * c2);
        float wa = __int_as_float(pa.y);
        float wb = __int_as_float(pb.y);
        a0 = fmaf(wa, bfu(ua.x), a0);
        a1 = fmaf(wa, bfu(ua.y), a1);
        b0 = fmaf(wb, bfu(ub.x), b0);
        b1 = fmaf(wb, bfu(ub.y), b1);
    }
    if (j < end) {
        int2 pa = epack[j];
        ushort2 ua = *(const ushort2*)(xw + pa.x * 64 + 2 * c2);
        float wa = __int_as_float(pa.y);
        a0 = fmaf(wa, bfu(ua.x), a0);
        a1 = fmaf(wa, bfu(ua.y), a1);
    }
    a0 += b0; a1 += b1;
    a0 += __shfl_xor(a0, 32);
    a1 += __shfl_xor(a1, 32);
    if (half == 0) {
        float di = dinv[node];
        ushort2 us = *(const ushort2*)(xw + node * 64 + 2 * c2);
        float2 bv = *(const float2*)(bias + 2 * c2);
        float o0 = fmaf(di, a0, fmaf(di * di, bfu(us.x), bv.x));
        float o1 = fmaf(di, a1, fmaf(di * di, bfu(us.y), bv.y));
        if (RELU) { o0 = fmaxf(o0, 0.f); o1 = fmaxf(o1, 0.f); }
        if constexpr (sizeof(OutT) == 2) {
            ushort2 sv; sv.x = fbf(o0); sv.y = fbf(o1);
            *(ushort2*)((ushort*)out + node * 64 + 2 * c2) = sv;
        } else {
            float2 fv; fv.x = o0; fv.y = o1;
            *(float2*)((float*)out + node * 64 + 2 * c2) = fv;
        }
    }
}

// ---------------- fused mean-pool + MLP head: 4 waves per graph ----------------
__global__ __launch_bounds__(256) void poolhead_kernel(const float* __restrict__ h,
                                                       const int* __restrict__ gbeg,
                                                       const int* __restrict__ gend,
                                                       const float* __restrict__ LW1,
                                                       const float* __restrict__ Lb1,
                                                       const float* __restrict__ LW2,
                                                       const float* __restrict__ Lb2,
                                                       float* __restrict__ out) {
    __shared__ float pp[4][64];
    __shared__ float p[64];
    __shared__ float t1[32];
    int g = blockIdx.x, t = threadIdx.x;
    int lane = t & 63, wid = t >> 6;
    int b = gbeg[g], e = gend[g];
    float acc = 0.f;
    for (int i = b + wid; i < e; i += 4) acc += h[i * 64 + lane];
    pp[wid][lane] = acc;
    __syncthreads();
    if (t < 64) {
        float s = pp[0][t] + pp[1][t] + pp[2][t] + pp[3][t];
        p[t] = s / fmaxf((float)(e - b), 1.0f);
    }
    __syncthreads();
    if (t < 32) {
        float a = Lb1[t];
#pragma unroll
        for (int k = 0; k < 64; ++k) a = fmaf(p[k], LW1[k * 32 + t], a);
        t1[t] = a;
    }
    __syncthreads();
    if (t < 10) {
        float a = Lb2[t];
#pragma unroll
        for (int j = 0; j < 32; ++j) a = fmaf(t1[j], LW2[j * 10 + t], a);
        out[g * 10 + t] = a;
    }
}

// ---------------- launch ----------------

extern "C" void kernel_launch(void* const* d_in, const int* in_sizes, int n_in,
                              void* d_out, int out_size, void* d_ws, size_t ws_size,
                              hipStream_t stream) {
    const float* x     = (const float*)d_in[0];
    const int*   ei    = (const int*)d_in[1];   // [2, NE]
    const float* ew    = (const float*)d_in[2];
    const int*   batch = (const int*)d_in[3];
    const float* W1    = (const float*)d_in[4];
    const float* b1    = (const float*)d_in[5];
    const float* W2    = (const float*)d_in[6];
    const float* b2    = (const float*)d_in[7];
    const float* LW1   = (const float*)d_in[8];
    const float* Lb1   = (const float*)d_in[9];
    const float* LW2   = (const float*)d_in[10];
    const float* Lb2   = (const float*)d_in[11];

    const int* src = ei;
    const int* dst = ei + NE;

    // workspace layout (4-byte units), aliasing exploits buffer lifetimes:
    float* ws = (float*)d_ws;
    unsigned long long* h64 = (unsigned long long*)ws;  // [NN] ull: 0 .. 100096
    int*   gbeg   = (int*)(ws + 100096);       // [NG] -> 100608
    int*   gend   = (int*)(ws + 100608);       // [NG] -> 101120  (zero range ends here)
    float* dinv   = ws + 101120;               // [NN]   -> 151168
    int*   rowptr = (int*)(ws + 151168);       // [NN+1] -> 201216
    int*   partial= (int*)(ws + 201216);       // [NB]   -> 201472
    int*   poff   = (int*)(ws + 201472);       // [NB]   -> 201728
    int2*  epack  = (int2*)(ws + 201728);      // [NE]   -> 1801728 (8B aligned)
    ushort* xwA   = (ushort*)(ws + 1801728);   // [NN*64] bf16: xw1, later xw2 -> 3401728
    ushort* h1    = (ushort*)(ws + 3401728);   // [NN*64] bf16 (dead after gemm64)
    float* h2     = ws + 3401728;              // [NN*64] fp32 overlays h1 -> 6601728
    int*   rank   = (int*)(ws + 6601728);      // [NE] (dead after scatter) -> 7401728
    // total 7401728 floats = 29.6 MB

    zero_kernel<<<(101120 + 255) / 256, 256, 0, stream>>>(ws, 101120);

    // CSR build + normalization (1 atomic per edge total)
    hist64_kernel<<<(NE + 255) / 256, 256, 0, stream>>>(dst, ew, h64, rank);
    dinv_scanA_kernel<<<NB, 256, 0, stream>>>(h64, dinv, partial);
    scanB_kernel<<<1, 256, 0, stream>>>(partial, poff);
    scanC_bounds_kernel<<<NB, 256, 0, stream>>>(h64, poff, rowptr, batch, gbeg, gend);
    scatter_kernel<<<(NE + 255) / 256, 256, 0, stream>>>(src, dst, ew, dinv, rowptr, rank, epack);

    // ---- layer 1 ----
    gemm_kernel<128, false><<<(NN + 63) / 64, 256, 0, stream>>>(x, W1, xwA);
    agg_kernel<true, ushort><<<(NN + 3) / 4, 256, 0, stream>>>(xwA, rowptr, epack, dinv, b1, h1);

    // ---- layer 2 ----
    gemm_kernel<64, true><<<(NN + 63) / 64, 256, 0, stream>>>(h1, W2, xwA);
    agg_kernel<false, float><<<(NN + 3) / 4, 256, 0, stream>>>(xwA, rowptr, epack, dinv, b2, h2);

    // ---- pool + head ----
    poolhead_kernel<<<NG, 256, 0, stream>>>(h2, gbeg, gend, LW1, Lb1, LW2, Lb2, (float*)d_out);
}

// Round 6
// 244.489 us; speedup vs baseline: 2.7802x; 1.0803x over previous
//
#include <hip/hip_runtime.h>
#include <hip/hip_bf16.h>

static constexpr int NN = 50000;   // nodes
static constexpr int NE = 800000;  // edges
static constexpr int NG = 512;     // graphs
static constexpr int NB = 196;     // 196*256 >= NN
static constexpr int HIST_BLOCKS = (NE + 255) / 256;  // 3125
static constexpr int GEMM_BLOCKS = (NN + 63) / 64;    // 782

__device__ __forceinline__ float bfu(ushort u) {
    return __uint_as_float((unsigned)u << 16);
}
__device__ __forceinline__ ushort fbf(float f) {
    return __hip_bfloat16_raw(__float2bfloat16(f)).x;
}

// ---------------- utility ----------------

__global__ void zero_kernel(float* __restrict__ p, int n) {
    int i = blockIdx.x * blockDim.x + threadIdx.x;
    if (i < n) p[i] = 0.f;
}

// ---------------- shared GEMM body: X [NN,K] @ W [K,64] -> out bf16 ----------------
// 64 rows/block, LDS-staged X + full W, 16x16 threads, 4x4 register tile.
template <int K, bool BF16IN>
__device__ __forceinline__ void gemm_body(const void* __restrict__ Xv,
                                          const float* __restrict__ W,
                                          ushort* __restrict__ out,
                                          int row0, float Xs[][68], float* Ws) {
    for (int i = threadIdx.x; i < K * 16; i += 256)
        ((float4*)Ws)[i] = ((const float4*)W)[i];
    int tx = threadIdx.x & 15, ty = threadIdx.x >> 4;
    float acc[4][4] = {};
    for (int kb = 0; kb < K; kb += 64) {
        __syncthreads();
        if constexpr (BF16IN) {
            const ushort* X = (const ushort*)Xv;
            for (int i = threadIdx.x; i < 512; i += 256) {   // 64 rows x 8 groups of 8 ch
                int r = i >> 3, g = i & 7;
                int gr = row0 + r; if (gr >= NN) gr = NN - 1;
                uint4 v = *(const uint4*)(X + (long long)gr * K + kb + g * 8);
                float4 f0, f1;
                f0.x = __uint_as_float(v.x << 16); f0.y = __uint_as_float(v.x & 0xffff0000u);
                f0.z = __uint_as_float(v.y << 16); f0.w = __uint_as_float(v.y & 0xffff0000u);
                f1.x = __uint_as_float(v.z << 16); f1.y = __uint_as_float(v.z & 0xffff0000u);
                f1.z = __uint_as_float(v.w << 16); f1.w = __uint_as_float(v.w & 0xffff0000u);
                *(float4*)&Xs[r][g * 8] = f0;
                *(float4*)&Xs[r][g * 8 + 4] = f1;
            }
        } else {
            const float* X = (const float*)Xv;
            for (int i = threadIdx.x; i < 1024; i += 256) {  // 64 rows x 16 float4
                int r = i >> 4, k4 = i & 15;
                int gr = row0 + r; if (gr >= NN) gr = NN - 1;
                float4 v = *(const float4*)(X + (long long)gr * K + kb + k4 * 4);
                *(float4*)&Xs[r][k4 * 4] = v;
            }
        }
        __syncthreads();
#pragma unroll 16
        for (int k = 0; k < 64; ++k) {
            float4 wv = *(const float4*)&Ws[(kb + k) * 64 + tx * 4];
            float x0 = Xs[ty * 4 + 0][k];
            float x1 = Xs[ty * 4 + 1][k];
            float x2 = Xs[ty * 4 + 2][k];
            float x3 = Xs[ty * 4 + 3][k];
            acc[0][0] = fmaf(x0, wv.x, acc[0][0]); acc[0][1] = fmaf(x0, wv.y, acc[0][1]);
            acc[0][2] = fmaf(x0, wv.z, acc[0][2]); acc[0][3] = fmaf(x0, wv.w, acc[0][3]);
            acc[1][0] = fmaf(x1, wv.x, acc[1][0]); acc[1][1] = fmaf(x1, wv.y, acc[1][1]);
            acc[1][2] = fmaf(x1, wv.z, acc[1][2]); acc[1][3] = fmaf(x1, wv.w, acc[1][3]);
            acc[2][0] = fmaf(x2, wv.x, acc[2][0]); acc[2][1] = fmaf(x2, wv.y, acc[2][1]);
            acc[2][2] = fmaf(x2, wv.z, acc[2][2]); acc[2][3] = fmaf(x2, wv.w, acc[2][3]);
            acc[3][0] = fmaf(x3, wv.x, acc[3][0]); acc[3][1] = fmaf(x3, wv.y, acc[3][1]);
            acc[3][2] = fmaf(x3, wv.z, acc[3][2]); acc[3][3] = fmaf(x3, wv.w, acc[3][3]);
        }
    }
#pragma unroll
    for (int j = 0; j < 4; ++j) {
        int r = row0 + ty * 4 + j;
        if (r < NN) {
            ushort4 sv;
            sv.x = fbf(acc[j][0]); sv.y = fbf(acc[j][1]);
            sv.z = fbf(acc[j][2]); sv.w = fbf(acc[j][3]);
            *(ushort4*)(out + (long long)r * 64 + tx * 4) = sv;
        }
    }
}

// ---------------- fused: hist64 (blocks 0..3124) || gemm128 (blocks 3125..3906) -------
// Both are independent; fusing lets the latency-bound atomic histogram overlap the
// VALU/LDS-bound GEMM within one serial-stream dispatch.
__global__ __launch_bounds__(256) void hist_gemm_kernel(const int* __restrict__ dst,
                                                        const float* __restrict__ ew,
                                                        unsigned long long* __restrict__ h,
                                                        int* __restrict__ rank,
                                                        const float* __restrict__ X,
                                                        const float* __restrict__ W,
                                                        ushort* __restrict__ out) {
    __shared__ float Xs[64][68];      // 2-way conflicts only (free)
    __shared__ float Ws[128 * 64];
    if (blockIdx.x < HIST_BLOCKS) {
        // one 64-bit atomic per edge: count in [40:64), sum(ew) fixed-point 2^-20 in [0:40)
        // returned old count = edge's rank within its dst group (free CSR fill counter)
        int e = blockIdx.x * 256 + threadIdx.x;
        if (e >= NE) return;
        int d = dst[e];
        unsigned int fx = __float2uint_rn(ew[e] * 1048576.0f);
        unsigned long long pack = (1ULL << 40) | (unsigned long long)fx;
        unsigned long long old = atomicAdd(&h[d], pack);
        rank[e] = (int)(old >> 40);
        return;
    }
    gemm_body<128, false>(X, W, out, (blockIdx.x - HIST_BLOCKS) * 64, Xs, Ws);
}

// standalone GEMM for layer 2 (bf16 input)
template <int K, bool BF16IN>
__global__ __launch_bounds__(256) void gemm_kernel(const void* __restrict__ Xv,
                                                   const float* __restrict__ W,
                                                   ushort* __restrict__ out) {
    __shared__ float Xs[64][68];
    __shared__ float Ws[K * 64];
    gemm_body<K, BF16IN>(Xv, W, out, blockIdx.x * 64, Xs, Ws);
}

// fused: dinv computation + per-block count reduction (scan phase A)
__global__ __launch_bounds__(256) void dinv_scanA_kernel(const unsigned long long* __restrict__ h,
                                                         float* __restrict__ dinv,
                                                         int* __restrict__ partial) {
    int i = blockIdx.x * 256 + threadIdx.x;
    int cnt = 0;
    if (i < NN) {
        unsigned long long v = h[i];
        cnt = (int)(v >> 40);
        float deg = (float)(v & ((1ULL << 40) - 1)) * (1.0f / 1048576.0f) + 1.0f;
        dinv[i] = 1.0f / sqrtf(deg);
    }
    __shared__ int wsum[4];
    int lane = threadIdx.x & 63, wid = threadIdx.x >> 6;
    int v = cnt;
#pragma unroll
    for (int off = 32; off > 0; off >>= 1) v += __shfl_down(v, (unsigned)off, 64);
    if (lane == 0) wsum[wid] = v;
    __syncthreads();
    if (threadIdx.x == 0) partial[blockIdx.x] = wsum[0] + wsum[1] + wsum[2] + wsum[3];
}

__device__ __forceinline__ int block_scan_inclusive(int v, int* wtot) {
    int lane = threadIdx.x & 63, wid = threadIdx.x >> 6;
    int inc = v;
#pragma unroll
    for (int off = 1; off < 64; off <<= 1) {
        int n = __shfl_up(inc, (unsigned)off, 64);
        if (lane >= off) inc += n;
    }
    if (lane == 63) wtot[wid] = inc;
    __syncthreads();
    int add = 0;
    for (int w = 0; w < wid; ++w) add += wtot[w];
    return inc + add;
}

// fused: per-block prefix of partials (scanB inlined) + rowptr finalize + graph bounds
__global__ __launch_bounds__(256) void scanC_bounds_kernel(const unsigned long long* __restrict__ h,
                                                           const int* __restrict__ partial,
                                                           int* __restrict__ rowptr,
                                                           const int* __restrict__ batch,
                                                           int* __restrict__ gbeg,
                                                           int* __restrict__ gend) {
    __shared__ int wtot[4];
    __shared__ int poff_s;
    int t = threadIdx.x;
    if (t < 64) {   // wave 0: poff = sum partial[0..bid-1]
        int s = 0;
        for (int i = t; i < (int)blockIdx.x; i += 64) s += partial[i];
#pragma unroll
        for (int off = 32; off > 0; off >>= 1) s += __shfl_down(s, (unsigned)off, 64);
        if (t == 0) poff_s = s;
    }
    int i = blockIdx.x * 256 + t;
    int v = (i < NN) ? (int)(h[i] >> 40) : 0;
    int incl = block_scan_inclusive(v, wtot);   // internal __syncthreads makes poff_s visible
    if (i < NN) {
        rowptr[i + 1] = poff_s + incl;
        int g = batch[i];
        if (i == 0 || batch[i - 1] != g) gbeg[g] = i;
        if (i == NN - 1 || batch[i + 1] != g) gend[g] = i + 1;
    }
    if (i == 0) rowptr[0] = 0;
}

// Atomic-free scatter: pos = rowptr[d] + rank[e]; epack[pos] = (src, dinv[s]*ew)
__global__ __launch_bounds__(256) void scatter_kernel(const int* __restrict__ src,
                                                      const int* __restrict__ dst,
                                                      const float* __restrict__ ew,
                                                      const float* __restrict__ dinv,
                                                      const int* __restrict__ rowptr,
                                                      const int* __restrict__ rank,
                                                      int2* __restrict__ epack) {
    int e = blockIdx.x * blockDim.x + threadIdx.x;
    if (e >= NE) return;
    int s = src[e], d = dst[e];
    int pos = rowptr[d] + rank[e];
    float coef = dinv[s] * ew[e];
    epack[pos] = make_int2(s, __float_as_int(coef));
}

// ---------------- CSR aggregation: one wave per node; quarter-waves x 4 ch/lane --------
// out[i,:] = bias + dinv[i]^2*xw[i,:] + dinv[i] * sum_j (dinv[s]*ew)_j * xw[src_j,:]
template <bool RELU>
__global__ __launch_bounds__(256) void agg_kernel(const ushort* __restrict__ xw,
                                                  const int* __restrict__ rowptr,
                                                  const int2* __restrict__ epack,
                                                  const float* __restrict__ dinv,
                                                  const float* __restrict__ bias,
                                                  ushort* __restrict__ out) {
    int node = blockIdx.x * 4 + (threadIdx.x >> 6);
    if (node >= NN) return;
    int lane = threadIdx.x & 63;
    int q = lane >> 4;       // edge slot within group of 4
    int l = lane & 15;       // channel group: ch 4l..4l+3
    int beg = rowptr[node], end = rowptr[node + 1];
    float a0 = 0.f, a1 = 0.f, a2 = 0.f, a3 = 0.f;
    float b0 = 0.f, b1 = 0.f, b2 = 0.f, b3 = 0.f;
    int j = beg + q;
    for (; j + 4 < end; j += 8) {
        int2 pA = epack[j];
        int2 pB = epack[j + 4];
        ushort4 uA = *(const ushort4*)(xw + pA.x * 64 + 4 * l);
        ushort4 uB = *(const ushort4*)(xw + pB.x * 64 + 4 * l);
        float wA = __int_as_float(pA.y);
        float wB = __int_as_float(pB.y);
        a0 = fmaf(wA, bfu(uA.x), a0); a1 = fmaf(wA, bfu(uA.y), a1);
        a2 = fmaf(wA, bfu(uA.z), a2); a3 = fmaf(wA, bfu(uA.w), a3);
        b0 = fmaf(wB, bfu(uB.x), b0); b1 = fmaf(wB, bfu(uB.y), b1);
        b2 = fmaf(wB, bfu(uB.z), b2); b3 = fmaf(wB, bfu(uB.w), b3);
    }
    if (j < end) {
        int2 pA = epack[j];
        ushort4 uA = *(const ushort4*)(xw + pA.x * 64 + 4 * l);
        float wA = __int_as_float(pA.y);
        a0 = fmaf(wA, bfu(uA.x), a0); a1 = fmaf(wA, bfu(uA.y), a1);
        a2 = fmaf(wA, bfu(uA.z), a2); a3 = fmaf(wA, bfu(uA.w), a3);
    }
    a0 += b0; a1 += b1; a2 += b2; a3 += b3;
    a0 += __shfl_xor(a0, 16); a0 += __shfl_xor(a0, 32);
    a1 += __shfl_xor(a1, 16); a1 += __shfl_xor(a1, 32);
    a2 += __shfl_xor(a2, 16); a2 += __shfl_xor(a2, 32);
    a3 += __shfl_xor(a3, 16); a3 += __shfl_xor(a3, 32);
    if (q == 0) {
        float di = dinv[node];
        float d2 = di * di;
        ushort4 us = *(const ushort4*)(xw + node * 64 + 4 * l);
        float4 bv = *(const float4*)(bias + 4 * l);
        float o0 = fmaf(di, a0, fmaf(d2, bfu(us.x), bv.x));
        float o1 = fmaf(di, a1, fmaf(d2, bfu(us.y), bv.y));
        float o2 = fmaf(di, a2, fmaf(d2, bfu(us.z), bv.z));
        float o3 = fmaf(di, a3, fmaf(d2, bfu(us.w), bv.w));
        if (RELU) {
            o0 = fmaxf(o0, 0.f); o1 = fmaxf(o1, 0.f);
            o2 = fmaxf(o2, 0.f); o3 = fmaxf(o3, 0.f);
        }
        ushort4 sv;
        sv.x = fbf(o0); sv.y = fbf(o1); sv.z = fbf(o2); sv.w = fbf(o3);
        *(ushort4*)(out + node * 64 + 4 * l) = sv;
    }
}

// ---------------- fused mean-pool + MLP head: 4 waves per graph (h is bf16) -----------
__global__ __launch_bounds__(256) void poolhead_kernel(const ushort* __restrict__ h,
                                                       const int* __restrict__ gbeg,
                                                       const int* __restrict__ gend,
                                                       const float* __restrict__ LW1,
                                                       const float* __restrict__ Lb1,
                                                       const float* __restrict__ LW2,
                                                       const float* __restrict__ Lb2,
                                                       float* __restrict__ out) {
    __shared__ float pp[4][64];
    __shared__ float p[64];
    __shared__ float t1[32];
    int g = blockIdx.x, t = threadIdx.x;
    int lane = t & 63, wid = t >> 6;
    int b = gbeg[g], e = gend[g];
    float acc = 0.f;
    for (int i = b + wid; i < e; i += 4) acc += bfu(h[i * 64 + lane]);
    pp[wid][lane] = acc;
    __syncthreads();
    if (t < 64) {
        float s = pp[0][t] + pp[1][t] + pp[2][t] + pp[3][t];
        p[t] = s / fmaxf((float)(e - b), 1.0f);
    }
    __syncthreads();
    if (t < 32) {
        float a = Lb1[t];
#pragma unroll
        for (int k = 0; k < 64; ++k) a = fmaf(p[k], LW1[k * 32 + t], a);
        t1[t] = a;
    }
    __syncthreads();
    if (t < 10) {
        float a = Lb2[t];
#pragma unroll
        for (int j = 0; j < 32; ++j) a = fmaf(t1[j], LW2[j * 10 + t], a);
        out[g * 10 + t] = a;
    }
}

// ---------------- launch ----------------

extern "C" void kernel_launch(void* const* d_in, const int* in_sizes, int n_in,
                              void* d_out, int out_size, void* d_ws, size_t ws_size,
                              hipStream_t stream) {
    const float* x     = (const float*)d_in[0];
    const int*   ei    = (const int*)d_in[1];   // [2, NE]
    const float* ew    = (const float*)d_in[2];
    const int*   batch = (const int*)d_in[3];
    const float* W1    = (const float*)d_in[4];
    const float* b1    = (const float*)d_in[5];
    const float* W2    = (const float*)d_in[6];
    const float* b2    = (const float*)d_in[7];
    const float* LW1   = (const float*)d_in[8];
    const float* Lb1   = (const float*)d_in[9];
    const float* LW2   = (const float*)d_in[10];
    const float* Lb2   = (const float*)d_in[11];

    const int* src = ei;
    const int* dst = ei + NE;

    // workspace layout (4-byte units)
    float* ws = (float*)d_ws;
    unsigned long long* h64 = (unsigned long long*)ws;  // [NN] ull: 0 .. 100096
    int*   gbeg   = (int*)(ws + 100096);       // [NG] -> 100608
    int*   gend   = (int*)(ws + 100608);       // [NG] -> 101120  (zero range ends here)
    float* dinv   = ws + 101120;               // [NN]   -> 151168
    int*   rowptr = (int*)(ws + 151168);       // [NN+1] -> 201216
    int*   partial= (int*)(ws + 201216);       // [NB]   -> 201472 (8B-aligned next)
    int2*  epack  = (int2*)(ws + 201472);      // [NE]   -> 1801472
    ushort* xwA   = (ushort*)(ws + 1801472);   // [NN*64] bf16: xw1, later xw2 -> 3401472
    ushort* h12   = (ushort*)(ws + 3401472);   // [NN*64] bf16: h1, later h2 -> 5001472
    int*   rank   = (int*)(ws + 5001472);      // [NE] (dead after scatter) -> 5801472
    // total 5801472 floats = 23.2 MB

    zero_kernel<<<(101120 + 255) / 256, 256, 0, stream>>>(ws, 101120);

    // hist64 (atomic CSR histogram, 1 atomic/edge) overlapped with gemm128 (x @ W1)
    hist_gemm_kernel<<<HIST_BLOCKS + GEMM_BLOCKS, 256, 0, stream>>>(dst, ew, h64, rank,
                                                                    x, W1, xwA);
    dinv_scanA_kernel<<<NB, 256, 0, stream>>>(h64, dinv, partial);
    scanC_bounds_kernel<<<NB, 256, 0, stream>>>(h64, partial, rowptr, batch, gbeg, gend);
    scatter_kernel<<<(NE + 255) / 256, 256, 0, stream>>>(src, dst, ew, dinv, rowptr, rank, epack);

    // ---- layer 1 aggregation ----
    agg_kernel<true><<<(NN + 3) / 4, 256, 0, stream>>>(xwA, rowptr, epack, dinv, b1, h12);

    // ---- layer 2 ----
    gemm_kernel<64, true><<<GEMM_BLOCKS, 256, 0, stream>>>(h12, W2, xwA);
    agg_kernel<false><<<(NN + 3) / 4, 256, 0, stream>>>(xwA, rowptr, epack, dinv, b2, h12);

    // ---- pool + head ----
    poolhead_kernel<<<NG, 256, 0, stream>>>(h12, gbeg, gend, LW1, Lb1, LW2, Lb2, (float*)d_out);
}